// Round 6
// baseline (670.834 us; speedup 1.0000x reference)
//
#include <hip/hip_runtime.h>
#include <hip/hip_fp16.h>
#include <math.h>

#define NN      65536
#define NE      1048576
#define NPER    1024
#define NGRAPH  64
#define KPER    512
#define IND     192
#define PED     64
#define HID     256
#define LAT     128

// workspace offsets (in 4-byte slots)
#define OFF_CNT     0u          // 65536 int
#define OFF_ROWPTR  65536u      // 65537 int
#define OFF_CUR     132096u     // 65536 int
#define OFF_DINV    198656u     // 65536 f
#define OFF_EPK     264192u     // 1048576 uint (src:16|normf16:16) + slack (2M reservation)
#define OFF_INVWN   2361344u    // 1 f
#define OFF_KEEP    2361360u    // 32768 int (also reused as bsum[256] during scan)
#define OFF_SCORE   2395136u    // 65536 f (raw pool dot, pre-tanh)
#define OFF_WT1     2460672u    // 65536 bf16 (32768 slots): W1^T
#define OFF_WT2     2493440u    // 65536 bf16: [Wmu|Wlv]^T
#define OFF_T0B     2526208u    // 16777216 fp8 slice-major [8][NN][32]: t0, reused as t1
#define OFF_HB      6720512u    // h bf16: 65536x256 ushort node-major; mu/lv overlay after gemm1
#define OFF_MUB     6720512u    // 65536x128 bf16
#define OFF_LVB     10914816u   // 65536x128 bf16

// d_out offsets (floats)
#define OUT_MU      4194304
#define OUT_LV      8388608
#define OUT_BATCH   12582912
#define OUT_PERM    12615680

typedef __attribute__((ext_vector_type(8))) short short8;
typedef __attribute__((ext_vector_type(4))) float floatx4;

__device__ __forceinline__ unsigned short f2bf(float f) {
    unsigned int u = __float_as_uint(f);
    u += 0x7FFFu + ((u >> 16) & 1u);
    return (unsigned short)(u >> 16);
}
__device__ __forceinline__ float bf2f(unsigned short u) {
    return __uint_as_float(((unsigned int)u) << 16);
}
// pack two f32 -> two bf16 (round-half-up) in one dword via v_perm
__device__ __forceinline__ unsigned int pack2bf(float x, float y) {
    const unsigned int ux = __float_as_uint(x) + 0x8000u;
    const unsigned int uy = __float_as_uint(y) + 0x8000u;
    return __builtin_amdgcn_perm(uy, ux, 0x07060302u);
}
// fp8 e5m2 = top byte of fp16 (round-nearest-even on truncate)
__device__ __forceinline__ unsigned char f2e5(float f) {
    unsigned short u = __half_as_ushort(__float2half(f));
    u += (unsigned short)(0x7Fu + ((u >> 8) & 1u));
    return (unsigned char)(u >> 8);
}
// pack 4 f32 -> 4 e5m2 bytes in one dword
__device__ __forceinline__ unsigned int pack4e5(float v0, float v1, float v2, float v3) {
#if __has_builtin(__builtin_amdgcn_cvt_pk_bf8_f32)
    const int t0 = __builtin_amdgcn_cvt_pk_bf8_f32(v0, v1, 0, false);
    return (unsigned int)__builtin_amdgcn_cvt_pk_bf8_f32(v2, v3, t0, true);
#else
    return (unsigned int)f2e5(v0) | ((unsigned int)f2e5(v1) << 8) |
           ((unsigned int)f2e5(v2) << 16) | ((unsigned int)f2e5(v3) << 24);
#endif
}
// bytes 0,1 of u -> half2 {b0<<8, b1<<8}; bytes 2,3 -> half2 {b2<<8, b3<<8}
__device__ __forceinline__ __half2 e5lo(unsigned int u) {
    return __builtin_bit_cast(__half2, __builtin_amdgcn_perm(u, 0u, 0x05000400u));
}
__device__ __forceinline__ __half2 e5hi(unsigned int u) {
    return __builtin_bit_cast(__half2, __builtin_amdgcn_perm(u, 0u, 0x07000600u));
}
// replicate high 16 bits (f16 norm) into both halves -> half2{norm, norm}
__device__ __forceinline__ __half2 meta2w(unsigned int m) {
    return __builtin_bit_cast(__half2, __builtin_amdgcn_perm(m, m, 0x07060706u));
}
__device__ __forceinline__ __half2 shflx_h2(__half2 x, int m) {
    return __builtin_bit_cast(__half2, __shfl_xor(__builtin_bit_cast(int, x), m, 64));
}

__global__ __launch_bounds__(256) void k_count(const int* __restrict__ ei, int* __restrict__ cnt) {
    const int g = blockIdx.x * 256 + threadIdx.x;
    const int4 d4 = *(const int4*)(ei + NE + g * 4);
    atomicAdd(&cnt[d4.x], 1);
    atomicAdd(&cnt[d4.y], 1);
    atomicAdd(&cnt[d4.z], 1);
    atomicAdd(&cnt[d4.w], 1);
}

// 3-phase multi-block exclusive scan of cnt -> rp; also dinv = rsqrt(cnt+1)
__global__ __launch_bounds__(256) void k_scanA(const int* __restrict__ cnt, int* __restrict__ rp,
                                               float* __restrict__ dinv, int* __restrict__ bsum) {
    __shared__ int sh[256];
    const int t = threadIdx.x, b = blockIdx.x;
    const int i = b * 256 + t;
    const int c = cnt[i];
    sh[t] = c;
    __syncthreads();
    for (int d = 1; d < 256; d <<= 1) {
        const int v = (t >= d) ? sh[t - d] : 0;
        __syncthreads();
        sh[t] += v;
        __syncthreads();
    }
    rp[i] = sh[t] - c;
    dinv[i] = 1.0f / sqrtf((float)(c + 1));
    if (t == 255) bsum[b] = sh[t];
}

__global__ __launch_bounds__(256) void k_scanB(int* __restrict__ bsum) {
    __shared__ int sh[256];
    const int t = threadIdx.x;
    const int c = bsum[t];
    sh[t] = c;
    __syncthreads();
    for (int d = 1; d < 256; d <<= 1) {
        const int v = (t >= d) ? sh[t - d] : 0;
        __syncthreads();
        sh[t] += v;
        __syncthreads();
    }
    bsum[t] = sh[t] - c;
}

__global__ __launch_bounds__(256) void k_scanC(int* __restrict__ rp, const int* __restrict__ bsum) {
    const int t = threadIdx.x, b = blockIdx.x;
    const int i = b * 256 + t;
    rp[i] += bsum[b];
    if (i == NN - 1) rp[NN] = NE;
}

// meta = (f16(norm) << 16) | src   (src < 65536 fits in 16 bits)
__global__ __launch_bounds__(256) void k_scatter(const int* __restrict__ ei, const int* __restrict__ rp,
                                                 int* __restrict__ cur, const float* __restrict__ dinv,
                                                 unsigned int* __restrict__ epk) {
    int e = blockIdx.x * 256 + threadIdx.x;
    int s = ei[e];
    int d = ei[NE + e];
    int pos = rp[d] + atomicAdd(&cur[d], 1);
    const unsigned short hn = __half_as_ushort(__float2half(dinv[s] * dinv[d]));
    epk[pos] = ((unsigned int)hn << 16) | (unsigned int)s;
}

__global__ __launch_bounds__(128) void k_wnorm(const float* __restrict__ wp, float* __restrict__ invwn) {
    __shared__ float red[128];
    int t = threadIdx.x;
    float v = wp[t];
    red[t] = v * v;
    __syncthreads();
    for (int s = 64; s > 0; s >>= 1) {
        if (t < s) red[t] += red[t + s];
        __syncthreads();
    }
    if (t == 0) invwn[0] = 1.0f / sqrtf(red[0]);
}

// transpose + bf16-convert weights: wt1[n][k] = W1[k][n]; wt2[n][k] = (Wmu|Wlv)[k][n]
__global__ __launch_bounds__(256) void k_prepw(const float* __restrict__ W1, const float* __restrict__ Wmu,
                                               const float* __restrict__ Wlv, unsigned short* __restrict__ wt1,
                                               unsigned short* __restrict__ wt2) {
    const int n = blockIdx.x, k = threadIdx.x;
    wt1[n * 256 + k] = f2bf(W1[k * 256 + n]);
    wt2[n * 256 + k] = f2bf((n < 128) ? Wmu[k * 128 + n] : Wlv[k * 128 + (n - 128)]);
}

// MFMA bf16 GEMM: C = A[N,256] @ B[256,256], C stored fp8 SLICE-MAJOR [8][NN][32B]
template <int MODE>
__global__ __launch_bounds__(256, 2) void k_gemm(const float* __restrict__ A0f, const float* __restrict__ A1f,
                                                 const unsigned short* __restrict__ Ah,
                                                 const unsigned short* __restrict__ Wt,
                                                 unsigned char* __restrict__ Cb) {
    __shared__ unsigned short lds[2][12288];
    const int tid = threadIdx.x;
    const int w = __builtin_amdgcn_readfirstlane(tid >> 6);
    const int lane = tid & 63;
    const int l = lane & 15, q = lane >> 4;
    const int Rbase = blockIdx.x * 128;
    const int mtb = (w >> 1) * 4;
    const int ntb = (w & 1) * 8;

    const int rs = tid >> 1;
    const int ch = tid & 1;
    const int stile = rs >> 4, sl = rs & 15, q0 = ch * 2;
    const int uA = (stile * 4 + q0) * 16 + sl;

    floatx4 acc[8][4];
#pragma unroll
    for (int j = 0; j < 8; ++j)
#pragma unroll
        for (int m = 0; m < 4; ++m) acc[j][m] = (floatx4)0.0f;

    auto stage = [&](int ks, int buf) {
        if (MODE == 0) {
            const float* p; int ld, col;
            const int k = ks * 32 + ch * 16;
            if (ks < 6) { p = A0f; ld = IND; col = k; }
            else        { p = A1f; ld = PED; col = k - IND; }
            const float* src = p + (size_t)(Rbase + rs) * ld + col;
            unsigned int pk[8];
#pragma unroll
            for (int j = 0; j < 16; j += 4) {
                const float4 t = *(const float4*)(src + j);
                pk[j / 2]     = pack2bf(t.x, t.y);
                pk[j / 2 + 1] = pack2bf(t.z, t.w);
            }
            *(uint4*)&lds[buf][uA * 8]        = *(uint4*)&pk[0];
            *(uint4*)&lds[buf][(uA + 16) * 8] = *(uint4*)&pk[4];
        } else {
            const unsigned short* src = Ah + (size_t)(Rbase + rs) * 256 + ks * 32 + ch * 16;
            *(uint4*)&lds[buf][uA * 8]        = ((const uint4*)src)[0];
            *(uint4*)&lds[buf][(uA + 16) * 8] = ((const uint4*)src)[1];
        }
#pragma unroll
        for (int rep = 0; rep < 2; ++rep) {
            const int n = rep * 128 + rs;
            const unsigned short* srcB = Wt + (size_t)n * 256 + ks * 32 + ch * 16;
            const uint4 w0 = ((const uint4*)srcB)[0];
            const uint4 w1 = ((const uint4*)srcB)[1];
            const int uB = ((n >> 4) * 4 + q0) * 16 + (n & 15);
            *(uint4*)&lds[buf][4096 + uB * 8]        = w0;
            *(uint4*)&lds[buf][4096 + (uB + 16) * 8] = w1;
        }
    };

    stage(0, 0);
    __syncthreads();
#pragma unroll
    for (int ks = 0; ks < 8; ++ks) {
        const int cur = ks & 1;
        if (ks < 7) stage(ks + 1, cur ^ 1);
        short8 a[4];
#pragma unroll
        for (int m = 0; m < 4; ++m)
            a[m] = *(const short8*)&lds[cur][(((mtb + m) * 4 + q) * 16 + l) * 8];
#pragma unroll
        for (int j = 0; j < 8; ++j) {
            const short8 b = *(const short8*)&lds[cur][4096 + (((ntb + j) * 4 + q) * 16 + l) * 8];
#pragma unroll
            for (int m = 0; m < 4; ++m)
                acc[j][m] = __builtin_amdgcn_mfma_f32_16x16x32_bf16(b, a[m], acc[j][m], 0, 0, 0);
        }
        if (ks < 7) __syncthreads();
    }

    // ---- store C (fp8, slice-major [col>>5][row][col&31]) ----
#pragma unroll
    for (int m = 0; m < 4; ++m) {
        const int row = Rbase + (mtb + m) * 16 + l;
#pragma unroll
        for (int j = 0; j < 8; ++j) {
            const int col = (ntb + j) * 16 + q * 4;
            const floatx4 v = acc[j][m];
            *(unsigned int*)(Cb + ((size_t)(col >> 5) * NN + row) * 32 + (col & 31)) =
                pack4e5(v[0], v[1], v[2], v[3]);
        }
    }
}

// column-sliced aggregation, wave-per-node schedule.
// block = 32 nodes x one 32-col slice (slice = blockIdx&7 -> XCD L2 residency).
// wave = 8 edge-slots x 8 col-dwords; processes its 8 nodes' CONTIGUOUS edge stream with a
// 3-stage (24-edge) pipeline whose stages advance uniformly by 8 edges and never drain at
// node boundaries (boundary stages re-consumed with masks lo<=idx<hi). End-of-node 8-way
// shfl_xor tree reduces the edge-slot partials; epilogue on e==0 lanes.
// PHASE 0: h = relu(acc + b1) -> bf16 hb (node-major)
// PHASE 1: mu/lv bf16 out + atomic partial pool-dot into score
template <int PHASE>
__global__ __launch_bounds__(256) void k_agg(const unsigned char* __restrict__ tb, const int* __restrict__ rp,
                                             const unsigned int* __restrict__ epk, const float* __restrict__ dinv,
                                             const float* __restrict__ bias0, const float* __restrict__ bias1,
                                             const float* __restrict__ eps, const float* __restrict__ wp,
                                             unsigned short* __restrict__ hb, unsigned short* __restrict__ mub,
                                             unsigned short* __restrict__ lvb, float* __restrict__ score) {
    const int tid = threadIdx.x;
    const int lane = tid & 63;
    const int e = lane >> 3;           // edge slot 0..7
    const int c = lane & 7;            // col dword 0..7
    const int slice = blockIdx.x & 7;
    const int nbase = (blockIdx.x >> 3) * 32 + (tid >> 6) * 8;
    const unsigned char* tsl = tb + ((size_t)slice * NN) * 32 + c * 4;
    const int ccol = slice * 32 + c * 4;
    const bool isLv = (PHASE == 1) && (slice >= 4);

    float4 bb, w4;
    if (PHASE == 0) {
        bb = *(const float4*)(bias0 + ccol);
    } else if (!isLv) {
        bb = *(const float4*)(bias0 + ccol);
        w4 = *(const float4*)(wp + ccol);
    } else {
        bb = *(const float4*)(bias1 + (ccol - 128));
        w4 = *(const float4*)(wp + (ccol - 128));
    }

    // stream pipeline prologue (overreads stay within epk's 2M-slot reservation;
    // garbage meta has src<65536 -> valid table row; masked to 0 before use)
    int b = rp[nbase];
    int be = b + e;
    unsigned int m0 = epk[be], m1 = epk[be + 8], m2 = epk[be + 16];
    unsigned int v0 = *(const unsigned int*)(tsl + ((size_t)(m0 & 0xFFFFu) << 5));
    unsigned int v1 = *(const unsigned int*)(tsl + ((size_t)(m1 & 0xFFFFu) << 5));
    unsigned int v2 = *(const unsigned int*)(tsl + ((size_t)(m2 & 0xFFFFu) << 5));

    int hi = b;
    for (int ni = 0; ni < 8; ++ni) {
        const int node = nbase + ni;
        const int lo = hi;
        hi = rp[node + 1];
        // prefetch epilogue operands (covered by edge loop)
        const float di = dinv[node];
        const unsigned int vs = *(const unsigned int*)(tsl + ((size_t)node << 5));
        float4 e4;
        if (isLv) e4 = *(const float4*)(eps + (size_t)node * 128 + (ccol - 128));

        const __half2 hz = __float2half2_rn(0.0f);
        __half2 a01 = hz, a23 = hz;
        for (;;) {
            const bool val = (be >= lo) && (be < hi);
            __half2 w = meta2w(m0);
            w = val ? w : hz;
            a01 = __hfma2(w, e5lo(v0), a01);
            a23 = __hfma2(w, e5hi(v0), a23);
            if (b + 8 > hi) break;
            m0 = m1; v0 = v1; m1 = m2; v1 = v2;
            b += 8; be += 8;
            m2 = epk[be + 16];
            v2 = *(const unsigned int*)(tsl + ((size_t)(m2 & 0xFFFFu) << 5));
        }
        // tree-reduce the 8 edge-slot partials (strides 8,16,32)
        a01 = __hadd2(a01, shflx_h2(a01, 8));
        a01 = __hadd2(a01, shflx_h2(a01, 16));
        a01 = __hadd2(a01, shflx_h2(a01, 32));
        a23 = __hadd2(a23, shflx_h2(a23, 8));
        a23 = __hadd2(a23, shflx_h2(a23, 16));
        a23 = __hadd2(a23, shflx_h2(a23, 32));
        if (e == 0) {
            const float2 flo = __half22float2(a01);
            const float2 fhi = __half22float2(a23);
            const float2 slo = __half22float2(e5lo(vs));
            const float2 shi = __half22float2(e5hi(vs));
            const float d2 = di * di;
            const float ax = fmaf(d2, slo.x, flo.x) + bb.x;
            const float ay = fmaf(d2, slo.y, flo.y) + bb.y;
            const float az = fmaf(d2, shi.x, fhi.x) + bb.z;
            const float aw = fmaf(d2, shi.y, fhi.y) + bb.w;
            if (PHASE == 0) {
                ushort4 r;
                r.x = f2bf(fmaxf(ax, 0.0f));
                r.y = f2bf(fmaxf(ay, 0.0f));
                r.z = f2bf(fmaxf(az, 0.0f));
                r.w = f2bf(fmaxf(aw, 0.0f));
                *(ushort4*)(hb + (size_t)node * 256 + ccol) = r;
            } else {
                ushort4 st;
                st.x = f2bf(ax); st.y = f2bf(ay); st.z = f2bf(az); st.w = f2bf(aw);
                float partial;
                if (!isLv) {
                    *(ushort4*)(mub + (size_t)node * 128 + ccol) = st;
                    partial = ax * w4.x + ay * w4.y + az * w4.z + aw * w4.w;
                } else {
                    *(ushort4*)(lvb + (size_t)node * 128 + (ccol - 128)) = st;
                    partial = e4.x * expf(0.5f * ax) * w4.x + e4.y * expf(0.5f * ay) * w4.y +
                              e4.z * expf(0.5f * az) * w4.z + e4.w * expf(0.5f * aw) * w4.w;
                }
                partial += __shfl_xor(partial, 1, 64);
                partial += __shfl_xor(partial, 2, 64);
                partial += __shfl_xor(partial, 4, 64);
                if (c == 0) atomicAdd(&score[node], partial);
            }
        }
    }
}

// per-graph bitonic top-k on RAW pool dot (tanh is monotone -> same ranking, ties same)
__global__ __launch_bounds__(512) void k_topk(const float* __restrict__ score, const int* __restrict__ batch,
                                              int* __restrict__ keep, float* __restrict__ out) {
    __shared__ float sk[1024];
    __shared__ int si[1024];
    const int g = blockIdx.x, t = threadIdx.x;
    for (int i = t; i < 1024; i += 512) {
        sk[i] = score[g * 1024 + i];
        si[i] = i;
    }
    __syncthreads();
    for (int k = 2; k <= 1024; k <<= 1) {
        for (int j = k >> 1; j > 0; j >>= 1) {
            for (int base = 0; base < 1024; base += 512) {
                int i = base + t;
                int ixj = i ^ j;
                if (ixj > i) {
                    float a = sk[i], b = sk[ixj];
                    int ia = si[i], ib = si[ixj];
                    bool before = (a > b) || (a == b && ia < ib);
                    bool up = ((i & k) == 0);
                    bool sw = up ? (!before) : before;
                    if (sw) {
                        sk[i] = b; si[i] = ib;
                        sk[ixj] = a; si[ixj] = ia;
                    }
                }
            }
            __syncthreads();
        }
    }
    if (t < KPER) {
        int node = g * 1024 + si[t];
        keep[g * KPER + t] = node;
        out[OUT_BATCH + g * KPER + t] = (float)batch[node];
        out[OUT_PERM + g * KPER + t] = (float)node;
    }
}

__global__ __launch_bounds__(128) void k_gather(const int* __restrict__ keep,
                                                const unsigned short* __restrict__ mub,
                                                const unsigned short* __restrict__ lvb,
                                                const float* __restrict__ eps,
                                                const float* __restrict__ score,
                                                const float* __restrict__ invwn, float* __restrict__ out) {
    const int kidx = blockIdx.x;
    const int c = threadIdx.x;
    const int node = keep[kidx];
    const float m = bf2f(mub[(size_t)node * 128 + c]);
    const float l = bf2f(lvb[(size_t)node * 128 + c]);
    const float e = eps[(size_t)node * 128 + c];
    const float z = fmaf(e, expf(0.5f * l), m);
    const float s = tanhf(score[node] * invwn[0]);
    out[(size_t)kidx * 128 + c] = z * s;
    out[OUT_MU + (size_t)kidx * 128 + c] = m;
    out[OUT_LV + (size_t)kidx * 128 + c] = l;
}

extern "C" void kernel_launch(void* const* d_in, const int* in_sizes, int n_in,
                              void* d_out, int out_size, void* d_ws, size_t ws_size,
                              hipStream_t stream) {
    (void)in_sizes; (void)n_in; (void)out_size; (void)ws_size;
    const float* x_raw = (const float*)d_in[0];
    const float* pe    = (const float*)d_in[1];
    const int*   ei    = (const int*)d_in[2];
    const int*   batch = (const int*)d_in[3];
    const float* eps   = (const float*)d_in[4];
    const float* W1    = (const float*)d_in[5];
    const float* b1    = (const float*)d_in[6];
    const float* Wmu   = (const float*)d_in[7];
    const float* bmu   = (const float*)d_in[8];
    const float* Wlv   = (const float*)d_in[9];
    const float* blv   = (const float*)d_in[10];
    const float* wp    = (const float*)d_in[11];
    float* ws = (float*)d_ws;
    int*  iws = (int*)d_ws;
    unsigned int* epk = (unsigned int*)(iws + OFF_EPK);
    unsigned short* wt1  = (unsigned short*)(ws + OFF_WT1);
    unsigned short* wt2  = (unsigned short*)(ws + OFF_WT2);
    unsigned char*  t0b  = (unsigned char*)(ws + OFF_T0B);
    unsigned short* hb16 = (unsigned short*)(ws + OFF_HB);
    unsigned short* mub  = (unsigned short*)(ws + OFF_MUB);
    unsigned short* lvb  = (unsigned short*)(ws + OFF_LVB);
    float* out = (float*)d_out;

    hipMemsetAsync(iws + OFF_CNT, 0, 65536 * 4, stream);
    hipMemsetAsync(iws + OFF_CUR, 0, 65536 * 4, stream);
    hipMemsetAsync(ws + OFF_SCORE, 0, 65536 * 4, stream);

    k_count<<<NE / 1024, 256, 0, stream>>>(ei, iws + OFF_CNT);
    k_scanA<<<256, 256, 0, stream>>>(iws + OFF_CNT, iws + OFF_ROWPTR, ws + OFF_DINV, iws + OFF_KEEP);
    k_scanB<<<1, 256, 0, stream>>>(iws + OFF_KEEP);
    k_scanC<<<256, 256, 0, stream>>>(iws + OFF_ROWPTR, iws + OFF_KEEP);
    k_scatter<<<NE / 256, 256, 0, stream>>>(ei, iws + OFF_ROWPTR, iws + OFF_CUR, ws + OFF_DINV, epk);
    k_wnorm<<<1, 128, 0, stream>>>(wp, ws + OFF_INVWN);
    k_prepw<<<256, 256, 0, stream>>>(W1, Wmu, Wlv, wt1, wt2);

    k_gemm<0><<<NN / 128, 256, 0, stream>>>(x_raw, pe, nullptr, wt1, t0b);
    k_agg<0><<<(NN / 32) * 8, 256, 0, stream>>>(t0b, iws + OFF_ROWPTR, epk, ws + OFF_DINV,
                                                b1, nullptr, nullptr, nullptr,
                                                hb16, nullptr, nullptr, nullptr);
    k_gemm<1><<<NN / 128, 256, 0, stream>>>(nullptr, nullptr, hb16, wt2, t0b);
    k_agg<1><<<(NN / 32) * 8, 256, 0, stream>>>(t0b, iws + OFF_ROWPTR, epk, ws + OFF_DINV,
                                                bmu, blv, eps, wp,
                                                nullptr, mub, lvb, ws + OFF_SCORE);
    k_topk<<<NGRAPH, 512, 0, stream>>>(ws + OFF_SCORE, batch, iws + OFF_KEEP, out);
    k_gather<<<NGRAPH * KPER, 128, 0, stream>>>(iws + OFF_KEEP, mub, lvb, eps,
                                                ws + OFF_SCORE, ws + OFF_INVWN, out);
}

// Round 7
// 414.779 us; speedup vs baseline: 1.6173x; 1.6173x over previous
//
#include <hip/hip_runtime.h>
#include <hip/hip_fp16.h>
#include <math.h>

#define NN      65536
#define NE      1048576
#define NPER    1024
#define NGRAPH  64
#define KPER    512
#define IND     192
#define PED     64
#define HID     256
#define LAT     128

// workspace offsets (in 4-byte slots)
#define OFF_CNT     0u          // 65536 int
#define OFF_ROWPTR  65536u      // 65537 int
#define OFF_CUR     132096u     // 65536 int
#define OFF_DINV    198656u     // 65536 f
#define OFF_EPK     264192u     // 1048576 int2 (src, norm) = 2097152 slots
#define OFF_INVWN   2361344u    // 1 f
#define OFF_KEEP    2361360u    // 32768 int (also reused as bsum[256] during scan)
#define OFF_SCORE   2395136u    // 65536 f
#define OFF_WT1     2460672u    // 65536 bf16 (32768 slots): W1^T
#define OFF_WT2     2493440u    // 65536 bf16: [Wmu|Wlv]^T
#define OFF_T0B     2526208u    // 16777216 fp8 node-major (4194304 slots): t0, reused as t1
#define OFF_HB      6720512u    // h bf16: 65536x256 ushort = 8388608 slots; mu/lv overlay after gemm1
#define OFF_MUB     6720512u    // 65536x128 bf16
#define OFF_LVB     10914816u   // 65536x128 bf16
// total ws end: 15109120 slots = 60.4 MB

// d_out offsets (floats)
#define OUT_MU      4194304
#define OUT_LV      8388608
#define OUT_BATCH   12582912
#define OUT_PERM    12615680

typedef __attribute__((ext_vector_type(8))) short short8;
typedef __attribute__((ext_vector_type(4))) float floatx4;

__device__ __forceinline__ unsigned short f2bf(float f) {
    unsigned int u = __float_as_uint(f);
    u += 0x7FFFu + ((u >> 16) & 1u);
    return (unsigned short)(u >> 16);
}
__device__ __forceinline__ float bf2f(unsigned short u) {
    return __uint_as_float(((unsigned int)u) << 16);
}
// pack two f32 -> two bf16 (round-half-up) in one dword via v_perm
__device__ __forceinline__ unsigned int pack2bf(float x, float y) {
    const unsigned int ux = __float_as_uint(x) + 0x8000u;
    const unsigned int uy = __float_as_uint(y) + 0x8000u;
    return __builtin_amdgcn_perm(uy, ux, 0x07060302u);
}
// fp8 e5m2 = top byte of fp16 (round-nearest-even on truncate)
__device__ __forceinline__ unsigned char f2e5(float f) {
    unsigned short u = __half_as_ushort(__float2half(f));
    u += (unsigned short)(0x7Fu + ((u >> 8) & 1u));
    return (unsigned char)(u >> 8);
}
// pack 4 f32 -> 4 e5m2 bytes in one dword
__device__ __forceinline__ unsigned int pack4e5(float v0, float v1, float v2, float v3) {
#if __has_builtin(__builtin_amdgcn_cvt_pk_bf8_f32)
    const int t0 = __builtin_amdgcn_cvt_pk_bf8_f32(v0, v1, 0, false);
    return (unsigned int)__builtin_amdgcn_cvt_pk_bf8_f32(v2, v3, t0, true);
#else
    return (unsigned int)f2e5(v0) | ((unsigned int)f2e5(v1) << 8) |
           ((unsigned int)f2e5(v2) << 16) | ((unsigned int)f2e5(v3) << 24);
#endif
}
// bytes 0,1 of u -> half2 {b0<<8, b1<<8}; bytes 2,3 -> half2 {b2<<8, b3<<8}
__device__ __forceinline__ __half2 e5lo(unsigned int u) {
    return __builtin_bit_cast(__half2, __builtin_amdgcn_perm(u, 0u, 0x05000400u));
}
__device__ __forceinline__ __half2 e5hi(unsigned int u) {
    return __builtin_bit_cast(__half2, __builtin_amdgcn_perm(u, 0u, 0x07000600u));
}

__global__ __launch_bounds__(256) void k_count(const int* __restrict__ ei, int* __restrict__ cnt) {
    const int g = blockIdx.x * 256 + threadIdx.x;
    const int4 d4 = *(const int4*)(ei + NE + g * 4);
    atomicAdd(&cnt[d4.x], 1);
    atomicAdd(&cnt[d4.y], 1);
    atomicAdd(&cnt[d4.z], 1);
    atomicAdd(&cnt[d4.w], 1);
}

// 3-phase multi-block exclusive scan of cnt -> rp; also dinv = rsqrt(cnt+1)
__global__ __launch_bounds__(256) void k_scanA(const int* __restrict__ cnt, int* __restrict__ rp,
                                               float* __restrict__ dinv, int* __restrict__ bsum) {
    __shared__ int sh[256];
    const int t = threadIdx.x, b = blockIdx.x;
    const int i = b * 256 + t;
    const int c = cnt[i];
    sh[t] = c;
    __syncthreads();
    for (int d = 1; d < 256; d <<= 1) {
        const int v = (t >= d) ? sh[t - d] : 0;
        __syncthreads();
        sh[t] += v;
        __syncthreads();
    }
    rp[i] = sh[t] - c;
    dinv[i] = 1.0f / sqrtf((float)(c + 1));
    if (t == 255) bsum[b] = sh[t];
}

__global__ __launch_bounds__(256) void k_scanB(int* __restrict__ bsum) {
    __shared__ int sh[256];
    const int t = threadIdx.x;
    const int c = bsum[t];
    sh[t] = c;
    __syncthreads();
    for (int d = 1; d < 256; d <<= 1) {
        const int v = (t >= d) ? sh[t - d] : 0;
        __syncthreads();
        sh[t] += v;
        __syncthreads();
    }
    bsum[t] = sh[t] - c;
}

__global__ __launch_bounds__(256) void k_scanC(int* __restrict__ rp, const int* __restrict__ bsum) {
    const int t = threadIdx.x, b = blockIdx.x;
    const int i = b * 256 + t;
    rp[i] += bsum[b];
    if (i == NN - 1) rp[NN] = NE;
}

__global__ __launch_bounds__(256) void k_scatter(const int* __restrict__ ei, const int* __restrict__ rp,
                                                 int* __restrict__ cur, const float* __restrict__ dinv,
                                                 int2* __restrict__ epk) {
    int e = blockIdx.x * 256 + threadIdx.x;
    int s = ei[e];
    int d = ei[NE + e];
    int pos = rp[d] + atomicAdd(&cur[d], 1);
    epk[pos] = make_int2(s, __float_as_int(dinv[s] * dinv[d]));
}

__global__ __launch_bounds__(128) void k_wnorm(const float* __restrict__ wp, float* __restrict__ invwn) {
    __shared__ float red[128];
    int t = threadIdx.x;
    float v = wp[t];
    red[t] = v * v;
    __syncthreads();
    for (int s = 64; s > 0; s >>= 1) {
        if (t < s) red[t] += red[t + s];
        __syncthreads();
    }
    if (t == 0) invwn[0] = 1.0f / sqrtf(red[0]);
}

// transpose + bf16-convert weights: wt1[n][k] = W1[k][n]; wt2[n][k] = (Wmu|Wlv)[k][n]
__global__ __launch_bounds__(256) void k_prepw(const float* __restrict__ W1, const float* __restrict__ Wmu,
                                               const float* __restrict__ Wlv, unsigned short* __restrict__ wt1,
                                               unsigned short* __restrict__ wt2) {
    const int n = blockIdx.x, k = threadIdx.x;
    wt1[n * 256 + k] = f2bf(W1[k * 256 + n]);
    wt2[n * 256 + k] = f2bf((n < 128) ? Wmu[k * 128 + n] : Wlv[k * 128 + (n - 128)]);
}

// MFMA bf16 GEMM: C[N,256](fp8 e5m2, node-major) = A[N,256] @ B[256,256]
// block: 256 thr = 4 waves, tile M=128 x N=256, K-step 32, double-buffered LDS.
// wave partition: 4 M-tiles x 8 N-tiles each -> 12 ds_read_b128/K-step.
// mfma operands swapped (b,a): lane acc quad = 4 consecutive columns of one C row
// -> epilogue packs 4 e5m2 bytes into one dword store (32 dword stores/thread).
template <int MODE>
__global__ __launch_bounds__(256, 2) void k_gemm(const float* __restrict__ A0f, const float* __restrict__ A1f,
                                                 const unsigned short* __restrict__ Ah,
                                                 const unsigned short* __restrict__ Wt,
                                                 unsigned char* __restrict__ Cb) {
    __shared__ unsigned short lds[2][12288];
    const int tid = threadIdx.x;
    const int w = __builtin_amdgcn_readfirstlane(tid >> 6);
    const int lane = tid & 63;
    const int l = lane & 15, q = lane >> 4;
    const int Rbase = blockIdx.x * 128;
    const int mtb = (w >> 1) * 4;
    const int ntb = (w & 1) * 8;

    const int rs = tid >> 1;
    const int ch = tid & 1;
    const int stile = rs >> 4, sl = rs & 15, q0 = ch * 2;
    const int uA = (stile * 4 + q0) * 16 + sl;

    floatx4 acc[8][4];
#pragma unroll
    for (int j = 0; j < 8; ++j)
#pragma unroll
        for (int m = 0; m < 4; ++m) acc[j][m] = (floatx4)0.0f;

    auto stage = [&](int ks, int buf) {
        if (MODE == 0) {
            const float* p; int ld, col;
            const int k = ks * 32 + ch * 16;
            if (ks < 6) { p = A0f; ld = IND; col = k; }
            else        { p = A1f; ld = PED; col = k - IND; }
            const float* src = p + (size_t)(Rbase + rs) * ld + col;
            unsigned int pk[8];
#pragma unroll
            for (int j = 0; j < 16; j += 4) {
                const float4 t = *(const float4*)(src + j);
                pk[j / 2]     = pack2bf(t.x, t.y);
                pk[j / 2 + 1] = pack2bf(t.z, t.w);
            }
            *(uint4*)&lds[buf][uA * 8]        = *(uint4*)&pk[0];
            *(uint4*)&lds[buf][(uA + 16) * 8] = *(uint4*)&pk[4];
        } else {
            const unsigned short* src = Ah + (size_t)(Rbase + rs) * 256 + ks * 32 + ch * 16;
            *(uint4*)&lds[buf][uA * 8]        = ((const uint4*)src)[0];
            *(uint4*)&lds[buf][(uA + 16) * 8] = ((const uint4*)src)[1];
        }
#pragma unroll
        for (int rep = 0; rep < 2; ++rep) {
            const int n = rep * 128 + rs;
            const unsigned short* srcB = Wt + (size_t)n * 256 + ks * 32 + ch * 16;
            const uint4 w0 = ((const uint4*)srcB)[0];
            const uint4 w1 = ((const uint4*)srcB)[1];
            const int uB = ((n >> 4) * 4 + q0) * 16 + (n & 15);
            *(uint4*)&lds[buf][4096 + uB * 8]        = w0;
            *(uint4*)&lds[buf][4096 + (uB + 16) * 8] = w1;
        }
    };

    stage(0, 0);
    __syncthreads();
#pragma unroll
    for (int ks = 0; ks < 8; ++ks) {
        const int cur = ks & 1;
        if (ks < 7) stage(ks + 1, cur ^ 1);
        short8 a[4];
#pragma unroll
        for (int m = 0; m < 4; ++m)
            a[m] = *(const short8*)&lds[cur][(((mtb + m) * 4 + q) * 16 + l) * 8];
#pragma unroll
        for (int j = 0; j < 8; ++j) {
            const short8 b = *(const short8*)&lds[cur][4096 + (((ntb + j) * 4 + q) * 16 + l) * 8];
#pragma unroll
            for (int m = 0; m < 4; ++m)
                acc[j][m] = __builtin_amdgcn_mfma_f32_16x16x32_bf16(b, a[m], acc[j][m], 0, 0, 0);
        }
        if (ks < 7) __syncthreads();
    }

    // ---- store C (fp8, node-major, packed dwords) ----
#pragma unroll
    for (int m = 0; m < 4; ++m) {
        unsigned char* rbase = Cb + (size_t)(Rbase + (mtb + m) * 16 + l) * 256 + q * 4;
#pragma unroll
        for (int j = 0; j < 8; ++j) {
            const floatx4 v = acc[j][m];
            *(unsigned int*)(rbase + (ntb + j) * 16) = pack4e5(v[0], v[1], v[2], v[3]);
        }
    }
}

__device__ __forceinline__ unsigned int gath(const unsigned char* tbc, int srcv) {
    return *(const unsigned int*)(tbc + ((size_t)__builtin_amdgcn_readfirstlane(srcv) << 8));
}

// aggregation: one wave per node, 4 fp8 columns per lane, packed half2 FMA.
// 2-stage software pipeline: meta oct k+2 issued first, gathers oct k+1, compute oct k.
// (r3 configuration: best measured at 57 us.)
// PHASE 0: out = relu(acc + b1) -> bf16 hb
// PHASE 1: cols 0..127 -> mu, 128..255 -> lv (bf16 out); also z & score
template <int PHASE>
__global__ __launch_bounds__(256) void k_agg(const unsigned char* __restrict__ tb, const int* __restrict__ rp,
                                             const int2* __restrict__ epk, const float* __restrict__ dinv,
                                             const float* __restrict__ bias0, const float* __restrict__ bias1,
                                             const float* __restrict__ eps, const float* __restrict__ wp,
                                             const float* __restrict__ invwn, unsigned short* __restrict__ hb,
                                             unsigned short* __restrict__ mub, unsigned short* __restrict__ lvb,
                                             float* __restrict__ score) {
    const int wv = __builtin_amdgcn_readfirstlane(threadIdx.x >> 6);
    const int lane = threadIdx.x & 63;
    const int node = blockIdx.x * 4 + wv;
    const int c0 = lane * 4;
    const float di = dinv[node];
    const unsigned char* tbc = tb + c0;

    // self contribution, weight di^2
    const unsigned int vs = *(const unsigned int*)(tbc + ((size_t)node << 8));
    const __half2 ws2 = __float2half2_rn(di * di);
    __half2 a01 = __hmul2(ws2, e5lo(vs));
    __half2 a23 = __hmul2(ws2, e5hi(vs));
    __half2 b01 = __float2half2_rn(0.0f);
    __half2 b23 = __float2half2_rn(0.0f);

    const int beg = rp[node], end = rp[node + 1];
    int p = beg;
    if (p + 8 <= end) {
        int2 em[8], en[8];
        unsigned int v[8];
#pragma unroll
        for (int i = 0; i < 8; ++i) em[i] = epk[p + i];          // meta oct0
#pragma unroll
        for (int i = 0; i < 8; ++i) v[i] = gath(tbc, em[i].x);   // gathers oct0
#pragma unroll
        for (int i = 0; i < 8; ++i) en[i] = epk[p + 8 + i];      // meta oct1 (overread in-ws)
        while (p + 16 <= end) {
            int2 ef[8];
#pragma unroll
            for (int i = 0; i < 8; ++i) ef[i] = epk[p + 16 + i]; // meta oct k+2 (no deps, first)
            unsigned int u[8];
#pragma unroll
            for (int i = 0; i < 8; ++i) u[i] = gath(tbc, en[i].x); // gathers oct k+1
#pragma unroll
            for (int i = 0; i < 8; i += 2) {                     // compute oct k
                const __half2 wA = __float2half2_rn(__int_as_float(em[i].y));
                const __half2 wB = __float2half2_rn(__int_as_float(em[i + 1].y));
                a01 = __hfma2(wA, e5lo(v[i]), a01);     a23 = __hfma2(wA, e5hi(v[i]), a23);
                b01 = __hfma2(wB, e5lo(v[i + 1]), b01); b23 = __hfma2(wB, e5hi(v[i + 1]), b23);
            }
#pragma unroll
            for (int i = 0; i < 8; ++i) { em[i] = en[i]; en[i] = ef[i]; v[i] = u[i]; }
            p += 8;
        }
#pragma unroll
        for (int i = 0; i < 8; i += 2) {                         // drain last full oct
            const __half2 wA = __float2half2_rn(__int_as_float(em[i].y));
            const __half2 wB = __float2half2_rn(__int_as_float(em[i + 1].y));
            a01 = __hfma2(wA, e5lo(v[i]), a01);     a23 = __hfma2(wA, e5hi(v[i]), a23);
            b01 = __hfma2(wB, e5lo(v[i + 1]), b01); b23 = __hfma2(wB, e5hi(v[i + 1]), b23);
        }
        p += 8;
    }
    if (p + 4 <= end) {
        const int2 e0 = epk[p], e1 = epk[p + 1], e2 = epk[p + 2], e3 = epk[p + 3];
        const unsigned int v0 = gath(tbc, e0.x);
        const unsigned int v1 = gath(tbc, e1.x);
        const unsigned int v2 = gath(tbc, e2.x);
        const unsigned int v3 = gath(tbc, e3.x);
        const __half2 w0 = __float2half2_rn(__int_as_float(e0.y));
        const __half2 w1 = __float2half2_rn(__int_as_float(e1.y));
        const __half2 w2 = __float2half2_rn(__int_as_float(e2.y));
        const __half2 w3 = __float2half2_rn(__int_as_float(e3.y));
        a01 = __hfma2(w0, e5lo(v0), a01); a23 = __hfma2(w0, e5hi(v0), a23);
        b01 = __hfma2(w1, e5lo(v1), b01); b23 = __hfma2(w1, e5hi(v1), b23);
        a01 = __hfma2(w2, e5lo(v2), a01); a23 = __hfma2(w2, e5hi(v2), a23);
        b01 = __hfma2(w3, e5lo(v3), b01); b23 = __hfma2(w3, e5hi(v3), b23);
        p += 4;
    }
    for (; p < end; ++p) {
        const int2 e = epk[p];
        const unsigned int v = gath(tbc, e.x);
        const __half2 w2 = __float2half2_rn(__int_as_float(e.y));
        a01 = __hfma2(w2, e5lo(v), a01);
        a23 = __hfma2(w2, e5hi(v), a23);
    }
    a01 = __hadd2(a01, b01);
    a23 = __hadd2(a23, b23);
    const float2 flo = __half22float2(a01);
    const float2 fhi = __half22float2(a23);
    float4 acc = make_float4(flo.x, flo.y, fhi.x, fhi.y);

    if (PHASE == 0) {
        const float4 bb = *(const float4*)(bias0 + c0);
        ushort4 r;
        r.x = f2bf(fmaxf(acc.x + bb.x, 0.0f));
        r.y = f2bf(fmaxf(acc.y + bb.y, 0.0f));
        r.z = f2bf(fmaxf(acc.z + bb.z, 0.0f));
        r.w = f2bf(fmaxf(acc.w + bb.w, 0.0f));
        *(ushort4*)(hb + ((size_t)node << 8) + c0) = r;
    } else {
        const int cb = (lane & 31) * 4;
        const float* bias = (lane < 32) ? bias0 : bias1;
        const float4 bb = *(const float4*)(bias + cb);
        acc.x += bb.x; acc.y += bb.y; acc.z += bb.z; acc.w += bb.w;
        unsigned short* dst = (lane < 32) ? mub : lvb;
        ushort4 st;
        st.x = f2bf(acc.x); st.y = f2bf(acc.y); st.z = f2bf(acc.z); st.w = f2bf(acc.w);
        *(ushort4*)(dst + (size_t)node * 128 + cb) = st;
        float4 l4;
        l4.x = __shfl(acc.x, lane | 32, 64);
        l4.y = __shfl(acc.y, lane | 32, 64);
        l4.z = __shfl(acc.z, lane | 32, 64);
        l4.w = __shfl(acc.w, lane | 32, 64);
        float partial = 0.0f;
        if (lane < 32) {
            const float4 e4 = *(const float4*)(eps + (size_t)node * 128 + cb);
            const float4 w4 = *(const float4*)(wp + cb);
            float zx = fmaf(e4.x, expf(0.5f * l4.x), acc.x);
            float zy = fmaf(e4.y, expf(0.5f * l4.y), acc.y);
            float zz = fmaf(e4.z, expf(0.5f * l4.z), acc.z);
            float zw = fmaf(e4.w, expf(0.5f * l4.w), acc.w);
            partial = zx * w4.x + zy * w4.y + zz * w4.z + zw * w4.w;
        }
        for (int off = 16; off > 0; off >>= 1) partial += __shfl_xor(partial, off, 64);
        if (lane == 0) score[node] = tanhf(partial * invwn[0]);
    }
}

// per-graph bitonic top-k: 1024 threads (one element each; no serial base loop),
// sort (score desc, idx asc), emit top 512
__global__ __launch_bounds__(1024) void k_topk(const float* __restrict__ score, const int* __restrict__ batch,
                                               int* __restrict__ keep, float* __restrict__ out) {
    __shared__ float sk[1024];
    __shared__ int si[1024];
    const int g = blockIdx.x, t = threadIdx.x;
    sk[t] = score[g * 1024 + t];
    si[t] = t;
    __syncthreads();
    for (int k = 2; k <= 1024; k <<= 1) {
        for (int j = k >> 1; j > 0; j >>= 1) {
            const int ixj = t ^ j;
            if (ixj > t) {
                float a = sk[t], b = sk[ixj];
                int ia = si[t], ib = si[ixj];
                bool before = (a > b) || (a == b && ia < ib);
                bool up = ((t & k) == 0);
                if (up ? (!before) : before) {
                    sk[t] = b; si[t] = ib;
                    sk[ixj] = a; si[ixj] = ia;
                }
            }
            __syncthreads();
        }
    }
    if (t < KPER) {
        int node = g * 1024 + si[t];
        keep[g * KPER + t] = node;
        out[OUT_BATCH + g * KPER + t] = (float)batch[node];
        out[OUT_PERM + g * KPER + t] = (float)node;
    }
}

__global__ __launch_bounds__(128) void k_gather(const int* __restrict__ keep,
                                                const unsigned short* __restrict__ mub,
                                                const unsigned short* __restrict__ lvb,
                                                const float* __restrict__ eps,
                                                const float* __restrict__ score, float* __restrict__ out) {
    const int kidx = blockIdx.x;
    const int c = threadIdx.x;
    const int node = keep[kidx];
    const float m = bf2f(mub[(size_t)node * 128 + c]);
    const float l = bf2f(lvb[(size_t)node * 128 + c]);
    const float e = eps[(size_t)node * 128 + c];
    const float z = fmaf(e, expf(0.5f * l), m);
    const float s = score[node];
    out[(size_t)kidx * 128 + c] = z * s;
    out[OUT_MU + (size_t)kidx * 128 + c] = m;
    out[OUT_LV + (size_t)kidx * 128 + c] = l;
}

extern "C" void kernel_launch(void* const* d_in, const int* in_sizes, int n_in,
                              void* d_out, int out_size, void* d_ws, size_t ws_size,
                              hipStream_t stream) {
    (void)in_sizes; (void)n_in; (void)out_size; (void)ws_size;
    const float* x_raw = (const float*)d_in[0];
    const float* pe    = (const float*)d_in[1];
    const int*   ei    = (const int*)d_in[2];
    const int*   batch = (const int*)d_in[3];
    const float* eps   = (const float*)d_in[4];
    const float* W1    = (const float*)d_in[5];
    const float* b1    = (const float*)d_in[6];
    const float* Wmu   = (const float*)d_in[7];
    const float* bmu   = (const float*)d_in[8];
    const float* Wlv   = (const float*)d_in[9];
    const float* blv   = (const float*)d_in[10];
    const float* wp    = (const float*)d_in[11];
    float* ws = (float*)d_ws;
    int*  iws = (int*)d_ws;
    int2* epk = (int2*)(iws + OFF_EPK);
    unsigned short* wt1  = (unsigned short*)(ws + OFF_WT1);
    unsigned short* wt2  = (unsigned short*)(ws + OFF_WT2);
    unsigned char*  t0b  = (unsigned char*)(ws + OFF_T0B);
    unsigned short* hb16 = (unsigned short*)(ws + OFF_HB);
    unsigned short* mub  = (unsigned short*)(ws + OFF_MUB);
    unsigned short* lvb  = (unsigned short*)(ws + OFF_LVB);
    float* out = (float*)d_out;

    hipMemsetAsync(iws + OFF_CNT, 0, 65536 * 4, stream);
    hipMemsetAsync(iws + OFF_CUR, 0, 65536 * 4, stream);

    k_count<<<NE / 1024, 256, 0, stream>>>(ei, iws + OFF_CNT);
    k_scanA<<<256, 256, 0, stream>>>(iws + OFF_CNT, iws + OFF_ROWPTR, ws + OFF_DINV, iws + OFF_KEEP);
    k_scanB<<<1, 256, 0, stream>>>(iws + OFF_KEEP);
    k_scanC<<<256, 256, 0, stream>>>(iws + OFF_ROWPTR, iws + OFF_KEEP);
    k_scatter<<<NE / 256, 256, 0, stream>>>(ei, iws + OFF_ROWPTR, iws + OFF_CUR, ws + OFF_DINV, epk);
    k_wnorm<<<1, 128, 0, stream>>>(wp, ws + OFF_INVWN);
    k_prepw<<<256, 256, 0, stream>>>(W1, Wmu, Wlv, wt1, wt2);

    k_gemm<0><<<NN / 128, 256, 0, stream>>>(x_raw, pe, nullptr, wt1, t0b);
    k_agg<0><<<NN / 4, 256, 0, stream>>>(t0b, iws + OFF_ROWPTR, epk, ws + OFF_DINV,
                                         b1, nullptr, nullptr, nullptr, nullptr,
                                         hb16, nullptr, nullptr, nullptr);
    k_gemm<1><<<NN / 128, 256, 0, stream>>>(nullptr, nullptr, hb16, wt2, t0b);
    k_agg<1><<<NN / 4, 256, 0, stream>>>(t0b, iws + OFF_ROWPTR, epk, ws + OFF_DINV,
                                         bmu, blv, eps, wp, ws + OFF_INVWN,
                                         nullptr, mub, lvb, ws + OFF_SCORE);
    k_topk<<<NGRAPH, 1024, 0, stream>>>(ws + OFF_SCORE, batch, iws + OFF_KEEP, out);
    k_gather<<<NGRAPH * KPER, 128, 0, stream>>>(iws + OFF_KEEP, mub, lvb, eps,
                                                ws + OFF_SCORE, out);
}